// Round 5
// baseline (282.087 us; speedup 1.0000x reference)
//
#include <hip/hip_runtime.h>

// Problem constants (fixed by the reference)
constexpr int NB  = 8;
constexpr int NC  = 64;
constexpr int NH  = 128;
constexpr int NW  = 128;
constexpr int NHW = NH * NW;          // 16384
constexpr int CHW = NC * NHW;         // 1048576
constexpr int SZ  = NB * CHW;         // 8388608 elements per tensor
constexpr int NPOS = NB * NHW;        // 131072 spatial positions
constexpr float EPS = 1e-5f;

using bf8   = __attribute__((ext_vector_type(8))) short;   // 8 bf16 = 4 VGPR
using f32x4 = __attribute__((ext_vector_type(4))) float;

static __device__ inline short f2bf(float f) {
    union { float f; unsigned int u; } v; v.f = f;
    unsigned int r = v.u + 0x7fffu + ((v.u >> 16) & 1u);   // RNE
    return (short)(r >> 16);
}

// ---------------------------------------------------------------------------
// (B,N,C) -> (B,C,H,W) transpose, LDS-tiled, coalesced both sides
__global__ void k_transpose(const float* __restrict__ x, float* __restrict__ xn) {
    __shared__ float t[64 * 65];
    int b   = blockIdx.x >> 8;
    int hw0 = (blockIdx.x & 255) << 6;
    int tid = threadIdx.x;
    #pragma unroll
    for (int k = 0; k < 16; ++k) {
        int idx = tid + (k << 8);
        int c = idx & 63, hwl = idx >> 6;
        t[c * 65 + hwl] = x[((size_t)b * NHW + hw0 + hwl) * NC + c];
    }
    __syncthreads();
    #pragma unroll
    for (int k = 0; k < 16; ++k) {
        int idx = tid + (k << 8);
        int hwl = idx & 63, c = idx >> 6;
        xn[(size_t)(b * NC + c) * NHW + hw0 + hwl] = t[c * 65 + hwl];
    }
}

// ---------------------------------------------------------------------------
// MFMA channel-linear (K=64). A = weights (rows d, staged LDS bf16 swizzled),
// B = input (cols = 16 positions/wave), D[d][pos]. Block = 4 waves = 64 pos.
// MODE 0: rollH (h-c)%H | 1: rollW (w-c)%W | 2: rollW (w+c)%W | 3: no roll
// WTRANS: weight in global is [d][c] (pc_w); else [c][d] (fc*)
template<int MODE, bool GELU_OUT, bool ADDXN, bool WTRANS, bool HASBIAS, bool BNRELU_IN>
__global__ __launch_bounds__(256) void
k_mfc(const float* __restrict__ in, const float* __restrict__ wgt,
      const float* __restrict__ bias, const float* __restrict__ xn,
      const float* __restrict__ meanc, const float* __restrict__ rstdc,
      const float* __restrict__ bng, const float* __restrict__ bnb,
      float* __restrict__ out) {
    __shared__ short wt[64 * 64];        // WT[d][c] bf16, swizzled c ^ ((d&7)<<3)
    __shared__ float scl[64], sft[64];
    int tid = threadIdx.x;
    int l = tid & 63, wv = tid >> 6;

    if (!WTRANS) {
        #pragma unroll
        for (int i = 0; i < 8; ++i) {
            int c0 = wv * 2 + i * 8;
            float v0 = wgt[c0 * 64 + l];
            float v1 = wgt[(c0 + 1) * 64 + l];
            unsigned int pk = (unsigned int)(unsigned short)f2bf(v0) |
                              ((unsigned int)(unsigned short)f2bf(v1) << 16);
            *(unsigned int*)&wt[l * 64 + (c0 ^ ((l & 7) << 3))] = pk;
        }
    } else {
        #pragma unroll
        for (int i = 0; i < 16; ++i) {
            int d = wv * 16 + i;
            wt[d * 64 + (l ^ ((d & 7) << 3))] = f2bf(wgt[d * 64 + l]);
        }
    }
    if (BNRELU_IN && tid < 64) {
        float s = rstdc[tid] * bng[tid];
        scl[tid] = s;
        sft[tid] = bnb[tid] - meanc[tid] * s;
    }
    __syncthreads();

    int q = l >> 4, col = l & 15;
    int p  = blockIdx.x * 64 + wv * 16 + col;
    int b  = p >> 14;
    int hw = p & (NHW - 1);
    int h  = hw >> 7, w = hw & 127;
    const float* inb = in + (size_t)b * CHW;

    f32x4 acc[4];
    #pragma unroll
    for (int dt = 0; dt < 4; ++dt) acc[dt] = (f32x4){0.f, 0.f, 0.f, 0.f};

    #pragma unroll
    for (int ks = 0; ks < 2; ++ks) {
        bf8 bfr;
        #pragma unroll
        for (int j = 0; j < 8; ++j) {
            int c = ks * 32 + q * 8 + j;
            int addr;
            if (MODE == 0)      addr = c * NHW + (((h - c) & 127) << 7) + w;
            else if (MODE == 1) addr = c * NHW + (h << 7) + ((w - c) & 127);
            else if (MODE == 2) addr = c * NHW + (h << 7) + ((w + c) & 127);
            else                addr = c * NHW + hw;
            float v = inb[addr];
            if (BNRELU_IN) v = fmaxf(v * scl[c] + sft[c], 0.f);
            bfr[j] = f2bf(v);
        }
        #pragma unroll
        for (int dt = 0; dt < 4; ++dt) {
            int d = dt * 16 + col;
            bf8 afr = *(bf8*)&wt[d * 64 + ((ks * 32 + q * 8) ^ ((d & 7) << 3))];
            acc[dt] = __builtin_amdgcn_mfma_f32_16x16x32_bf16(afr, bfr, acc[dt], 0, 0, 0);
        }
    }

    size_t obase = (size_t)b * CHW + hw;
    #pragma unroll
    for (int dt = 0; dt < 4; ++dt) {
        #pragma unroll
        for (int r = 0; r < 4; ++r) {
            int d = dt * 16 + q * 4 + r;
            float val = acc[dt][r];
            if (HASBIAS) val += bias[d];
            if (GELU_OUT) val = 0.5f * val * (1.f + erff(val * 0.70710678118654752f));
            size_t oa = obase + (size_t)d * NHW;
            if (ADDXN) val += xn[oa];
            out[oa] = val;
        }
    }
}

// ---------------------------------------------------------------------------
// Tiny: P[d] = sum_c g[c]*w5[c][d], Q[d] = sum_c b[c]*w5[c][d]
__global__ void k_pq(const float* __restrict__ w5, const float* __restrict__ lng,
                     const float* __restrict__ lnb, float* __restrict__ PQ) {
    int d = threadIdx.x;   // 64
    float P = 0.f, Q = 0.f;
    for (int c = 0; c < 128; ++c) {
        float wv = w5[c * 64 + d];
        P += lng[c] * wv;
        Q += lnb[c] * wv;
    }
    PQ[d] = P; PQ[64 + d] = Q;
}

// ---------------------------------------------------------------------------
// LN(concat(x_1,x_2)) @ fc5 + b5 + xn via MFMA, K=128, LN folded:
// out = rstd*(A@(g.*W)) + Q - m*rstd*P + b5 + xn. Stats via shfl_xor.
__global__ __launch_bounds__(256) void
k_mln(const float* __restrict__ x1p, const float* __restrict__ x2p,
      const float* __restrict__ w5, const float* __restrict__ lng,
      const float* __restrict__ PQ, const float* __restrict__ b5,
      const float* __restrict__ xn, float* __restrict__ out) {
    __shared__ short wt[64 * 128];       // WT[d][c'] = g[c']*w5[c'][d], swizzled
    int tid = threadIdx.x;
    int l = tid & 63, wv = tid >> 6;

    #pragma unroll
    for (int i = 0; i < 16; ++i) {
        int c0 = wv * 2 + i * 8;
        float v0 = lng[c0]     * w5[c0 * 64 + l];
        float v1 = lng[c0 + 1] * w5[(c0 + 1) * 64 + l];
        unsigned int pk = (unsigned int)(unsigned short)f2bf(v0) |
                          ((unsigned int)(unsigned short)f2bf(v1) << 16);
        *(unsigned int*)&wt[l * 128 + (c0 ^ ((l & 7) << 3))] = pk;
    }
    __syncthreads();

    int q = l >> 4, col = l & 15;
    int p  = blockIdx.x * 64 + wv * 16 + col;
    int b  = p >> 14;
    int hw = p & (NHW - 1);

    f32x4 acc[4];
    #pragma unroll
    for (int dt = 0; dt < 4; ++dt) acc[dt] = (f32x4){0.f, 0.f, 0.f, 0.f};

    float ss = 0.f, sq = 0.f;
    #pragma unroll
    for (int ks = 0; ks < 4; ++ks) {
        const float* src = (ks < 2) ? x1p : x2p;
        const float* sb  = src + (size_t)b * CHW + hw;
        bf8 bfr;
        #pragma unroll
        for (int j = 0; j < 8; ++j) {
            int c = (ks * 32 + q * 8 + j) & 63;
            float v = sb[(size_t)c * NHW];
            ss += v; sq += v * v;
            bfr[j] = f2bf(v);
        }
        #pragma unroll
        for (int dt = 0; dt < 4; ++dt) {
            int d = dt * 16 + col;
            bf8 afr = *(bf8*)&wt[d * 128 + ((ks * 32 + q * 8) ^ ((d & 7) << 3))];
            acc[dt] = __builtin_amdgcn_mfma_f32_16x16x32_bf16(afr, bfr, acc[dt], 0, 0, 0);
        }
    }
    ss += __shfl_xor(ss, 16); ss += __shfl_xor(ss, 32);
    sq += __shfl_xor(sq, 16); sq += __shfl_xor(sq, 32);
    float m    = ss * (1.f / 128.f);
    float var  = sq * (1.f / 128.f) - m * m;
    float rstd = rsqrtf(var + EPS);
    float mr   = m * rstd;

    size_t obase = (size_t)b * CHW + hw;
    #pragma unroll
    for (int dt = 0; dt < 4; ++dt) {
        #pragma unroll
        for (int r = 0; r < 4; ++r) {
            int d = dt * 16 + q * 4 + r;
            float val = rstd * acc[dt][r] + PQ[64 + d] - mr * PQ[d] + b5[d];
            size_t oa = obase + (size_t)d * NHW;
            out[oa] = val + xn[oa];
        }
    }
}

// ---------------------------------------------------------------------------
// Depthwise 3x3 conv (float4 outputs) + fused BN plane-stats of own output.
// Block = 256 threads = 8 rows of ONE (b,c) plane. Stats -> atomicAdd per c.
// BNIN: apply per-channel BN affine + relu to loaded inputs (pad stays 0).
template<int DIL, bool HASBIAS, bool BNIN>
__global__ __launch_bounds__(256) void
k_dwconv4(const float* __restrict__ in, const float* __restrict__ wgt,
          const float* __restrict__ bias,
          const float* __restrict__ meanc, const float* __restrict__ rstdc,
          const float* __restrict__ bng, const float* __restrict__ bnb,
          float* __restrict__ out, float* __restrict__ csum, float* __restrict__ csq) {
    int t  = blockIdx.x * 256 + threadIdx.x;   // float4 index over SZ/4
    int w4 = t & 31;
    int h  = (t >> 5) & 127;
    int bc = t >> 12;
    int c  = bc & 63;
    const float* ip = in + (size_t)bc * NHW;

    float wc[9];
    #pragma unroll
    for (int k = 0; k < 9; ++k) wc[k] = wgt[c * 9 + k];
    float scale = 0.f, shift = 0.f;
    if (BNIN) { scale = rstdc[c] * bng[c]; shift = bnb[c] - meanc[c] * scale; }

    float o0, o1, o2, o3;
    o0 = o1 = o2 = o3 = HASBIAS ? bias[c] : 0.f;

    #pragma unroll
    for (int i = 0; i < 3; ++i) {
        int hh = h + (i - 1) * DIL;
        if (hh < 0 || hh >= NH) continue;
        const float* rp = ip + hh * NW + w4 * 4;
        float4 m4 = *(const float4*)rp;
        float4 l4 = (w4 > 0)  ? *(const float4*)(rp - 4) : make_float4(0.f, 0.f, 0.f, 0.f);
        float4 r4 = (w4 < 31) ? *(const float4*)(rp + 4) : make_float4(0.f, 0.f, 0.f, 0.f);
        float win[12] = {l4.x, l4.y, l4.z, l4.w, m4.x, m4.y, m4.z, m4.w,
                         r4.x, r4.y, r4.z, r4.w};
        if (BNIN) {
            #pragma unroll
            for (int j = 0; j < 12; ++j) win[j] = fmaxf(win[j] * scale + shift, 0.f);
        }
        if (w4 == 0)  { win[2] = 0.f; win[3] = 0.f; }    // zero-pad left (DIL<=2)
        if (w4 == 31) { win[8] = 0.f; win[9] = 0.f; }    // zero-pad right
        float wr0 = wc[i * 3], wr1 = wc[i * 3 + 1], wr2 = wc[i * 3 + 2];
        o0 += wr0 * win[4 - DIL] + wr1 * win[4] + wr2 * win[4 + DIL];
        o1 += wr0 * win[5 - DIL] + wr1 * win[5] + wr2 * win[5 + DIL];
        o2 += wr0 * win[6 - DIL] + wr1 * win[6] + wr2 * win[6 + DIL];
        o3 += wr0 * win[7 - DIL] + wr1 * win[7] + wr2 * win[7 + DIL];
    }
    *(float4*)(out + (size_t)t * 4) = make_float4(o0, o1, o2, o3);

    // fused plane stats (whole block shares one (b,c))
    float s = o0 + o1 + o2 + o3;
    float q = o0 * o0 + o1 * o1 + o2 * o2 + o3 * o3;
    __shared__ float ss[256], sq[256];
    ss[threadIdx.x] = s; sq[threadIdx.x] = q; __syncthreads();
    for (int o = 128; o > 0; o >>= 1) {
        if (threadIdx.x < o) { ss[threadIdx.x] += ss[threadIdx.x + o];
                               sq[threadIdx.x] += sq[threadIdx.x + o]; }
        __syncthreads();
    }
    if (threadIdx.x == 0) { atomicAdd(&csum[c], ss[0]); atomicAdd(&csq[c], sq[0]); }
}

// zero the 4x64 stat accumulators (run each launch -> replay-safe)
__global__ void k_zero(float* __restrict__ p) {
    p[threadIdx.x] = 0.f;   // 256 threads, 256 floats
}

__global__ void k_bn_finalize(const float* __restrict__ csum, const float* __restrict__ csq,
                              float* __restrict__ meanc, float* __restrict__ rstdc) {
    int c = threadIdx.x;  // 64 threads
    const float inv = 1.f / (float)(NB * NHW);
    float m = csum[c] * inv;
    float v = csq[c] * inv - m * m;
    meanc[c] = m;
    rstdc[c] = rsqrtf(v + EPS);
}

// ---------------------------------------------------------------------------
// SE partial: s4[bc*4+q] = sum_{quarter} x2*y3 ; grid = 2048, float4 loads
__global__ void k_se_reduce(const float* __restrict__ x2, const float* __restrict__ y3,
                            float* __restrict__ s4) {
    __shared__ float ss[256];
    int q   = blockIdx.x & 3;
    int bc  = blockIdx.x >> 2;
    int tid = threadIdx.x;
    const float4* a  = (const float4*)(x2 + (size_t)bc * NHW + q * (NHW / 4));
    const float4* b_ = (const float4*)(y3 + (size_t)bc * NHW + q * (NHW / 4));
    float acc = 0.f;
    #pragma unroll
    for (int i = 0; i < 4; ++i) {
        float4 av = a[tid + i * 256], bv = b_[tid + i * 256];
        acc += av.x * bv.x + av.y * bv.y + av.z * bv.z + av.w * bv.w;
    }
    ss[tid] = acc; __syncthreads();
    for (int o = 128; o > 0; o >>= 1) {
        if (tid < o) ss[tid] += ss[tid + o];
        __syncthreads();
    }
    if (tid == 0) s4[blockIdx.x] = ss[0];
}

// e[b,c] = sigmoid(W2 @ relu(W1 @ s + b1) + b2) ; one block (64 threads) per b
__global__ void k_se_mlp(const float* __restrict__ s4, const float* __restrict__ w1,
                         const float* __restrict__ b1, const float* __restrict__ w2,
                         const float* __restrict__ b2, float* __restrict__ e) {
    __shared__ float sh[64], e1[8];
    int b = blockIdx.x, tid = threadIdx.x;
    float sv = 0.f;
    #pragma unroll
    for (int j = 0; j < 4; ++j) sv += s4[(b * 64 + tid) * 4 + j];
    sh[tid] = sv * (4.f / (float)NHW);
    __syncthreads();
    if (tid < 8) {
        float a = b1[tid];
        for (int c = 0; c < 64; ++c) a += sh[c] * w1[tid * 64 + c];
        e1[tid] = a > 0.f ? a : 0.f;
    }
    __syncthreads();
    float a = b2[tid];
    #pragma unroll
    for (int j = 0; j < 8; ++j) a += e1[j] * w2[tid * 8 + j];
    e[b * 64 + tid] = 1.f / (1.f + expf(-a));
}

// out = 4*x2*y3*(1+e), float4
__global__ void k_final4(const float4* __restrict__ x2, const float4* __restrict__ y3,
                         const float* __restrict__ e, float4* __restrict__ out) {
    int t  = blockIdx.x * 256 + threadIdx.x;
    int bc = t >> 12;
    float f = 4.f * (1.f + e[bc]);
    float4 a = x2[t], y = y3[t];
    out[t] = make_float4(f * a.x * y.x, f * a.y * y.y, f * a.z * y.z, f * a.w * y.w);
}

// ---------------------------------------------------------------------------
extern "C" void kernel_launch(void* const* d_in, const int* in_sizes, int n_in,
                              void* d_out, int out_size, void* d_ws, size_t ws_size,
                              hipStream_t stream) {
    const float* x     = (const float*)d_in[0];
    const float* fc1w  = (const float*)d_in[1];
    const float* fc1b  = (const float*)d_in[2];
    const float* fc2w  = (const float*)d_in[3];
    const float* fc2b  = (const float*)d_in[4];
    const float* fc3w  = (const float*)d_in[5];
    const float* fc3b  = (const float*)d_in[6];
    const float* fc4w  = (const float*)d_in[7];
    const float* fc4b  = (const float*)d_in[8];
    const float* fc5w  = (const float*)d_in[9];
    const float* fc5b  = (const float*)d_in[10];
    const float* lng   = (const float*)d_in[11];
    const float* lnb   = (const float*)d_in[12];
    const float* pcw   = (const float*)d_in[13];
    const float* dww   = (const float*)d_in[14];
    const float* dwb   = (const float*)d_in[15];
    const float* dwbng = (const float*)d_in[16];
    const float* dwbnb = (const float*)d_in[17];
    const float* ddw   = (const float*)d_in[18];
    const float* ddbng = (const float*)d_in[19];
    const float* ddbnb = (const float*)d_in[20];
    const float* sew1  = (const float*)d_in[21];
    const float* seb1  = (const float*)d_in[22];
    const float* sew2  = (const float*)d_in[23];
    const float* seb2  = (const float*)d_in[24];

    float* out  = (float*)d_out;
    float* ws   = (float*)d_ws;
    float* buf0 = ws;                      // xn, later x2
    float* buf1 = ws + (size_t)SZ;         // t1, x_2, d1, y3
    float* buf2 = ws + (size_t)2 * SZ;     // t2, x1, d2
    float* st   = ws + (size_t)3 * SZ;
    float* csum1  = st;          // 64
    float* csq1   = st + 64;     // 64
    float* csum2  = st + 128;    // 64
    float* csq2   = st + 192;    // 64
    float* meanc1 = st + 256;    // 64
    float* rstdc1 = st + 320;    // 64
    float* meanc2 = st + 384;    // 64
    float* rstdc2 = st + 448;    // 64
    float* svec   = st + 512;    // 2048
    float* evec   = st + 2560;   // 512
    float* pqv    = st + 3072;   // 128

    dim3 blk(256);
    const float* nil = nullptr;

    // zero BN stat accumulators (csum1..csq2, 256 floats)
    k_zero<<<1, 256, 0, stream>>>(csum1);
    // xn = transpose(x)
    k_transpose<<<NB * (NHW / 64), blk, 0, stream>>>(x, buf0);
    // P,Q for folded LN
    k_pq<<<1, 64, 0, stream>>>(fc5w, lng, lnb, pqv);
    // t1 = gelu(fc1(roll_h(xn,+1)))
    k_mfc<0, true,  false, false, true, false><<<NPOS / 64, blk, 0, stream>>>(buf0, fc1w, fc1b, nil, nil, nil, nil, nil, buf1);
    // t2 = gelu(fc3(roll_w(xn,-1)))
    k_mfc<2, true,  false, false, true, false><<<NPOS / 64, blk, 0, stream>>>(buf0, fc3w, fc3b, nil, nil, nil, nil, nil, buf2);
    // x_1 = fc2(roll_w(t1,+1)) + xn   (d_out used as scratch, fully rewritten later)
    k_mfc<1, false, true,  false, true, false><<<NPOS / 64, blk, 0, stream>>>(buf1, fc2w, fc2b, buf0, nil, nil, nil, nil, out);
    // x_2 = fc4(roll_h(t2,+1)) + xn
    k_mfc<0, false, true,  false, true, false><<<NPOS / 64, blk, 0, stream>>>(buf2, fc4w, fc4b, buf0, nil, nil, nil, nil, buf1);
    // x1 = LN(concat(x_1,x_2)) @ fc5 + b5 + xn
    k_mln<<<NPOS / 64, blk, 0, stream>>>(out, buf1, fc5w, lng, pqv, fc5b, buf0, buf2);
    // x2 = pc(x1)
    k_mfc<3, false, false, true, false, false><<<NPOS / 64, blk, 0, stream>>>(buf2, pcw, nil, nil, nil, nil, nil, nil, buf0);
    // d1 = dwconv3x3(x2, dil=1) + dw_b   [stats fused]
    k_dwconv4<1, true, false><<<SZ / 1024, blk, 0, stream>>>(buf0, dww, dwb, nil, nil, nil, nil, buf1, csum1, csq1);
    k_bn_finalize<<<1, 64, 0, stream>>>(csum1, csq1, meanc1, rstdc1);
    // d2 = dwconv3x3(relu(bn1(d1)), dil=2)   [BN fused into load, stats fused]
    k_dwconv4<2, false, true><<<SZ / 1024, blk, 0, stream>>>(buf1, ddw, nil, meanc1, rstdc1, dwbng, dwbnb, buf2, csum2, csq2);
    k_bn_finalize<<<1, 64, 0, stream>>>(csum2, csq2, meanc2, rstdc2);
    // y3 = pc(relu(bn2(d2)))                 [BN+relu fused into load]
    k_mfc<3, false, false, true, false, true><<<NPOS / 64, blk, 0, stream>>>(buf2, pcw, nil, nil, meanc2, rstdc2, ddbng, ddbnb, buf1);
    // SE + final: out = 4*x2*y3*(1+e)
    k_se_reduce<<<NB * NC * 4, blk, 0, stream>>>(buf0, buf1, svec);
    k_se_mlp<<<NB, 64, 0, stream>>>(svec, sew1, seb1, sew2, seb2, evec);
    k_final4<<<SZ / 1024, blk, 0, stream>>>((const float4*)buf0, (const float4*)buf1, evec, (float4*)out);
}

// Round 6
// 216.384 us; speedup vs baseline: 1.3036x; 1.3036x over previous
//
#include <hip/hip_runtime.h>

// Problem constants (fixed by the reference)
constexpr int NB  = 8;
constexpr int NC  = 64;
constexpr int NH  = 128;
constexpr int NW  = 128;
constexpr int NHW = NH * NW;          // 16384
constexpr int CHW = NC * NHW;         // 1048576
constexpr int SZ  = NB * CHW;         // 8388608 elements per tensor
constexpr int NPOS = NB * NHW;        // 131072 spatial positions
constexpr float EPS = 1e-5f;

using bf8   = __attribute__((ext_vector_type(8))) short;   // 8 bf16 = 4 VGPR
using f32x4 = __attribute__((ext_vector_type(4))) float;

static __device__ inline short f2bf(float f) {
    union { float f; unsigned int u; } v; v.f = f;
    unsigned int r = v.u + 0x7fffu + ((v.u >> 16) & 1u);   // RNE
    return (short)(r >> 16);
}

// ---------------------------------------------------------------------------
// (B,N,C) -> (B,C,H,W) transpose, LDS-tiled, coalesced both sides
__global__ void k_transpose(const float* __restrict__ x, float* __restrict__ xn) {
    __shared__ float t[64 * 65];
    int b   = blockIdx.x >> 8;
    int hw0 = (blockIdx.x & 255) << 6;
    int tid = threadIdx.x;
    #pragma unroll
    for (int k = 0; k < 16; ++k) {
        int idx = tid + (k << 8);
        int c = idx & 63, hwl = idx >> 6;
        t[c * 65 + hwl] = x[((size_t)b * NHW + hw0 + hwl) * NC + c];
    }
    __syncthreads();
    #pragma unroll
    for (int k = 0; k < 16; ++k) {
        int idx = tid + (k << 8);
        int hwl = idx & 63, c = idx >> 6;
        xn[(size_t)(b * NC + c) * NHW + hw0 + hwl] = t[c * 65 + hwl];
    }
}

// ---------------------------------------------------------------------------
// MFMA channel-linear (K=64). A = weights (rows d, staged LDS bf16 swizzled),
// B = input (cols = 16 positions/wave), D[d][pos]. Block = 4 waves = 64 pos.
// MODE 0: rollH (h-c)%H | 1: rollW (w-c)%W | 2: rollW (w+c)%W | 3: no roll
// WTRANS: weight in global is [d][c] (pc_w); else [c][d] (fc*)
template<int MODE, bool GELU_OUT, bool ADDXN, bool WTRANS, bool HASBIAS, bool BNRELU_IN>
__global__ __launch_bounds__(256) void
k_mfc(const float* __restrict__ in, const float* __restrict__ wgt,
      const float* __restrict__ bias, const float* __restrict__ xn,
      const float* __restrict__ meanc, const float* __restrict__ rstdc,
      const float* __restrict__ bng, const float* __restrict__ bnb,
      float* __restrict__ out) {
    __shared__ short wt[64 * 64];        // WT[d][c] bf16, swizzled c ^ ((d&7)<<3)
    __shared__ float scl[64], sft[64];
    int tid = threadIdx.x;
    int l = tid & 63, wv = tid >> 6;

    if (!WTRANS) {
        #pragma unroll
        for (int i = 0; i < 8; ++i) {
            int c0 = wv * 2 + i * 8;
            float v0 = wgt[c0 * 64 + l];
            float v1 = wgt[(c0 + 1) * 64 + l];
            unsigned int pk = (unsigned int)(unsigned short)f2bf(v0) |
                              ((unsigned int)(unsigned short)f2bf(v1) << 16);
            *(unsigned int*)&wt[l * 64 + (c0 ^ ((l & 7) << 3))] = pk;
        }
    } else {
        #pragma unroll
        for (int i = 0; i < 16; ++i) {
            int d = wv * 16 + i;
            wt[d * 64 + (l ^ ((d & 7) << 3))] = f2bf(wgt[d * 64 + l]);
        }
    }
    if (BNRELU_IN && tid < 64) {
        float s = rstdc[tid] * bng[tid];
        scl[tid] = s;
        sft[tid] = bnb[tid] - meanc[tid] * s;
    }
    __syncthreads();

    int q = l >> 4, col = l & 15;
    int p  = blockIdx.x * 64 + wv * 16 + col;
    int b  = p >> 14;
    int hw = p & (NHW - 1);
    int h  = hw >> 7, w = hw & 127;
    const float* inb = in + (size_t)b * CHW;

    f32x4 acc[4];
    #pragma unroll
    for (int dt = 0; dt < 4; ++dt) acc[dt] = (f32x4){0.f, 0.f, 0.f, 0.f};

    #pragma unroll
    for (int ks = 0; ks < 2; ++ks) {
        bf8 bfr;
        #pragma unroll
        for (int j = 0; j < 8; ++j) {
            int c = ks * 32 + q * 8 + j;
            int addr;
            if (MODE == 0)      addr = c * NHW + (((h - c) & 127) << 7) + w;
            else if (MODE == 1) addr = c * NHW + (h << 7) + ((w - c) & 127);
            else if (MODE == 2) addr = c * NHW + (h << 7) + ((w + c) & 127);
            else                addr = c * NHW + hw;
            float v = inb[addr];
            if (BNRELU_IN) v = fmaxf(v * scl[c] + sft[c], 0.f);
            bfr[j] = f2bf(v);
        }
        #pragma unroll
        for (int dt = 0; dt < 4; ++dt) {
            int d = dt * 16 + col;
            bf8 afr = *(bf8*)&wt[d * 64 + ((ks * 32 + q * 8) ^ ((d & 7) << 3))];
            acc[dt] = __builtin_amdgcn_mfma_f32_16x16x32_bf16(afr, bfr, acc[dt], 0, 0, 0);
        }
    }

    size_t obase = (size_t)b * CHW + hw;
    #pragma unroll
    for (int dt = 0; dt < 4; ++dt) {
        #pragma unroll
        for (int r = 0; r < 4; ++r) {
            int d = dt * 16 + q * 4 + r;
            float val = acc[dt][r];
            if (HASBIAS) val += bias[d];
            if (GELU_OUT) val = 0.5f * val * (1.f + erff(val * 0.70710678118654752f));
            size_t oa = obase + (size_t)d * NHW;
            if (ADDXN) val += xn[oa];
            out[oa] = val;
        }
    }
}

// ---------------------------------------------------------------------------
// Tiny: P[d] = sum_c g[c]*w5[c][d], Q[d] = sum_c b[c]*w5[c][d]
__global__ void k_pq(const float* __restrict__ w5, const float* __restrict__ lng,
                     const float* __restrict__ lnb, float* __restrict__ PQ) {
    int d = threadIdx.x;   // 64
    float P = 0.f, Q = 0.f;
    for (int c = 0; c < 128; ++c) {
        float wv = w5[c * 64 + d];
        P += lng[c] * wv;
        Q += lnb[c] * wv;
    }
    PQ[d] = P; PQ[64 + d] = Q;
}

// ---------------------------------------------------------------------------
// LN(concat(x_1,x_2)) @ fc5 + b5 + xn via MFMA, K=128, LN folded:
// out = rstd*(A@(g.*W)) + Q - m*rstd*P + b5 + xn. Stats via shfl_xor.
__global__ __launch_bounds__(256) void
k_mln(const float* __restrict__ x1p, const float* __restrict__ x2p,
      const float* __restrict__ w5, const float* __restrict__ lng,
      const float* __restrict__ PQ, const float* __restrict__ b5,
      const float* __restrict__ xn, float* __restrict__ out) {
    __shared__ short wt[64 * 128];       // WT[d][c'] = g[c']*w5[c'][d], swizzled
    int tid = threadIdx.x;
    int l = tid & 63, wv = tid >> 6;

    #pragma unroll
    for (int i = 0; i < 16; ++i) {
        int c0 = wv * 2 + i * 8;
        float v0 = lng[c0]     * w5[c0 * 64 + l];
        float v1 = lng[c0 + 1] * w5[(c0 + 1) * 64 + l];
        unsigned int pk = (unsigned int)(unsigned short)f2bf(v0) |
                          ((unsigned int)(unsigned short)f2bf(v1) << 16);
        *(unsigned int*)&wt[l * 128 + (c0 ^ ((l & 7) << 3))] = pk;
    }
    __syncthreads();

    int q = l >> 4, col = l & 15;
    int p  = blockIdx.x * 64 + wv * 16 + col;
    int b  = p >> 14;
    int hw = p & (NHW - 1);

    f32x4 acc[4];
    #pragma unroll
    for (int dt = 0; dt < 4; ++dt) acc[dt] = (f32x4){0.f, 0.f, 0.f, 0.f};

    float ss = 0.f, sq = 0.f;
    #pragma unroll
    for (int ks = 0; ks < 4; ++ks) {
        const float* src = (ks < 2) ? x1p : x2p;
        const float* sb  = src + (size_t)b * CHW + hw;
        bf8 bfr;
        #pragma unroll
        for (int j = 0; j < 8; ++j) {
            int c = (ks * 32 + q * 8 + j) & 63;
            float v = sb[(size_t)c * NHW];
            ss += v; sq += v * v;
            bfr[j] = f2bf(v);
        }
        #pragma unroll
        for (int dt = 0; dt < 4; ++dt) {
            int d = dt * 16 + col;
            bf8 afr = *(bf8*)&wt[d * 128 + ((ks * 32 + q * 8) ^ ((d & 7) << 3))];
            acc[dt] = __builtin_amdgcn_mfma_f32_16x16x32_bf16(afr, bfr, acc[dt], 0, 0, 0);
        }
    }
    ss += __shfl_xor(ss, 16); ss += __shfl_xor(ss, 32);
    sq += __shfl_xor(sq, 16); sq += __shfl_xor(sq, 32);
    float m    = ss * (1.f / 128.f);
    float var  = sq * (1.f / 128.f) - m * m;
    float rstd = rsqrtf(var + EPS);
    float mr   = m * rstd;

    size_t obase = (size_t)b * CHW + hw;
    #pragma unroll
    for (int dt = 0; dt < 4; ++dt) {
        #pragma unroll
        for (int r = 0; r < 4; ++r) {
            int d = dt * 16 + q * 4 + r;
            float val = rstd * acc[dt][r] + PQ[64 + d] - mr * PQ[d] + b5[d];
            size_t oa = obase + (size_t)d * NHW;
            out[oa] = val + xn[oa];
        }
    }
}

// ---------------------------------------------------------------------------
// Depthwise 3x3 conv, LDS-tiled: block = 32 rows of one (b,c) plane (grid 2048,
// XCD-chunk swizzled). Stage 36 rows (+/-2 halo) into LDS with BN+relu applied
// at stage time; zero pads materialized (aligned 4-float side pads, stride 136).
// Stats of own output -> per-block partials (no atomics).
template<int DIL, bool HASBIAS, bool BNIN>
__global__ __launch_bounds__(256) void
k_dwlds(const float* __restrict__ in, const float* __restrict__ wgt,
        const float* __restrict__ bias,
        const float* __restrict__ meanc, const float* __restrict__ rstdc,
        const float* __restrict__ bng, const float* __restrict__ bnb,
        float* __restrict__ out, float* __restrict__ psum, float* __restrict__ psq) {
    constexpr int STR = 136;                  // 4 pad | 128 | 4 pad
    __shared__ float tile[36 * STR];          // 19.1 KB
    __shared__ float ss[256], sq[256];

    int blk = ((blockIdx.x & 7) << 8) | (blockIdx.x >> 3);  // XCD chunk swizzle (2048%8==0, bijective)
    int q   = blk & 3;                        // plane quarter
    int bc  = blk >> 2;                       // (b*64+c) plane
    int c   = bc & 63;
    int r0  = q * 32;
    int tid = threadIdx.x;
    const float* ip = in + (size_t)bc * NHW;

    float scale = 0.f, shift = 0.f;
    if (BNIN) { scale = rstdc[c] * bng[c]; shift = bnb[c] - meanc[c] * scale; }

    // stage rows r0-2 .. r0+33 (zero outside plane), BN+relu at stage time
    for (int idx = tid; idx < 36 * 32; idx += 256) {
        int lr = idx >> 5, c4 = idx & 31;
        int gr = r0 - 2 + lr;
        float4 v = make_float4(0.f, 0.f, 0.f, 0.f);
        if (gr >= 0 && gr < NH) {
            v = *(const float4*)(ip + gr * NW + c4 * 4);
            if (BNIN) {
                v.x = fmaxf(v.x * scale + shift, 0.f);
                v.y = fmaxf(v.y * scale + shift, 0.f);
                v.z = fmaxf(v.z * scale + shift, 0.f);
                v.w = fmaxf(v.w * scale + shift, 0.f);
            }
        }
        *(float4*)&tile[lr * STR + 4 + c4 * 4] = v;
        if (c4 == 0)  *(float4*)&tile[lr * STR]       = make_float4(0.f, 0.f, 0.f, 0.f);
        if (c4 == 31) *(float4*)&tile[lr * STR + 132] = make_float4(0.f, 0.f, 0.f, 0.f);
    }
    __syncthreads();

    float wc[9];
    #pragma unroll
    for (int k = 0; k < 9; ++k) wc[k] = wgt[c * 9 + k];

    int row  = tid >> 3;                      // 0..31 (8 threads per row)
    int col0 = (tid & 7) * 16;                // 16 outputs per thread
    float o[16];
    float bb = HASBIAS ? bias[c] : 0.f;
    #pragma unroll
    for (int j = 0; j < 16; ++j) o[j] = bb;

    #pragma unroll
    for (int i = 0; i < 3; ++i) {
        const float* rp = &tile[(row + 2 + (i - 1) * DIL) * STR + 4 + col0];
        float4 A  = *(const float4*)(rp - 4);
        float4 B0 = *(const float4*)(rp);
        float4 B1 = *(const float4*)(rp + 4);
        float4 B2 = *(const float4*)(rp + 8);
        float4 B3 = *(const float4*)(rp + 12);
        float4 Cc = *(const float4*)(rp + 16);
        float ww[24] = {A.x,A.y,A.z,A.w, B0.x,B0.y,B0.z,B0.w, B1.x,B1.y,B1.z,B1.w,
                        B2.x,B2.y,B2.z,B2.w, B3.x,B3.y,B3.z,B3.w, Cc.x,Cc.y,Cc.z,Cc.w};
        float w0 = wc[3 * i], w1 = wc[3 * i + 1], w2 = wc[3 * i + 2];
        #pragma unroll
        for (int j = 0; j < 16; ++j)
            o[j] += w0 * ww[4 + j - DIL] + w1 * ww[4 + j] + w2 * ww[4 + j + DIL];
    }

    float* op = out + (size_t)bc * NHW + (r0 + row) * NW + col0;
    *(float4*)(op)      = make_float4(o[0],  o[1],  o[2],  o[3]);
    *(float4*)(op + 4)  = make_float4(o[4],  o[5],  o[6],  o[7]);
    *(float4*)(op + 8)  = make_float4(o[8],  o[9],  o[10], o[11]);
    *(float4*)(op + 12) = make_float4(o[12], o[13], o[14], o[15]);

    // fused plane-quarter stats -> per-block partials (no atomics)
    float s = 0.f, qq = 0.f;
    #pragma unroll
    for (int j = 0; j < 16; ++j) { s += o[j]; qq += o[j] * o[j]; }
    ss[tid] = s; sq[tid] = qq; __syncthreads();
    for (int off = 128; off > 0; off >>= 1) {
        if (tid < off) { ss[tid] += ss[tid + off]; sq[tid] += sq[tid + off]; }
        __syncthreads();
    }
    if (tid == 0) { psum[blk] = ss[0]; psq[blk] = sq[0]; }
}

// finalize: per channel c, sum 8 b x 4 q partials
__global__ void k_bn_finalize(const float* __restrict__ psum, const float* __restrict__ psq,
                              float* __restrict__ meanc, float* __restrict__ rstdc) {
    int c = threadIdx.x;  // 64 threads
    float s = 0.f, qv = 0.f;
    for (int b = 0; b < NB; ++b)
        #pragma unroll
        for (int j = 0; j < 4; ++j) {
            int idx = ((b * 64 + c) << 2) + j;
            s += psum[idx]; qv += psq[idx];
        }
    const float inv = 1.f / (float)(NB * NHW);
    float m = s * inv;
    float v = qv * inv - m * m;
    meanc[c] = m;
    rstdc[c] = rsqrtf(v + EPS);
}

// ---------------------------------------------------------------------------
// SE partial: s4[bc*4+q] = sum_{quarter} x2*y3 ; grid = 2048, float4 loads
__global__ void k_se_reduce(const float* __restrict__ x2, const float* __restrict__ y3,
                            float* __restrict__ s4) {
    __shared__ float ss[256];
    int q   = blockIdx.x & 3;
    int bc  = blockIdx.x >> 2;
    int tid = threadIdx.x;
    const float4* a  = (const float4*)(x2 + (size_t)bc * NHW + q * (NHW / 4));
    const float4* b_ = (const float4*)(y3 + (size_t)bc * NHW + q * (NHW / 4));
    float acc = 0.f;
    #pragma unroll
    for (int i = 0; i < 4; ++i) {
        float4 av = a[tid + i * 256], bv = b_[tid + i * 256];
        acc += av.x * bv.x + av.y * bv.y + av.z * bv.z + av.w * bv.w;
    }
    ss[tid] = acc; __syncthreads();
    for (int o = 128; o > 0; o >>= 1) {
        if (tid < o) ss[tid] += ss[tid + o];
        __syncthreads();
    }
    if (tid == 0) s4[blockIdx.x] = ss[0];
}

// e[b,c] = sigmoid(W2 @ relu(W1 @ s + b1) + b2) ; one block (64 threads) per b
__global__ void k_se_mlp(const float* __restrict__ s4, const float* __restrict__ w1,
                         const float* __restrict__ b1, const float* __restrict__ w2,
                         const float* __restrict__ b2, float* __restrict__ e) {
    __shared__ float sh[64], e1[8];
    int b = blockIdx.x, tid = threadIdx.x;
    float sv = 0.f;
    #pragma unroll
    for (int j = 0; j < 4; ++j) sv += s4[(b * 64 + tid) * 4 + j];
    sh[tid] = sv * (4.f / (float)NHW);
    __syncthreads();
    if (tid < 8) {
        float a = b1[tid];
        for (int c = 0; c < 64; ++c) a += sh[c] * w1[tid * 64 + c];
        e1[tid] = a > 0.f ? a : 0.f;
    }
    __syncthreads();
    float a = b2[tid];
    #pragma unroll
    for (int j = 0; j < 8; ++j) a += e1[j] * w2[tid * 8 + j];
    e[b * 64 + tid] = 1.f / (1.f + expf(-a));
}

// out = 4*x2*y3*(1+e), float4
__global__ void k_final4(const float4* __restrict__ x2, const float4* __restrict__ y3,
                         const float* __restrict__ e, float4* __restrict__ out) {
    int t  = blockIdx.x * 256 + threadIdx.x;
    int bc = t >> 12;
    float f = 4.f * (1.f + e[bc]);
    float4 a = x2[t], y = y3[t];
    out[t] = make_float4(f * a.x * y.x, f * a.y * y.y, f * a.z * y.z, f * a.w * y.w);
}

// ---------------------------------------------------------------------------
extern "C" void kernel_launch(void* const* d_in, const int* in_sizes, int n_in,
                              void* d_out, int out_size, void* d_ws, size_t ws_size,
                              hipStream_t stream) {
    const float* x     = (const float*)d_in[0];
    const float* fc1w  = (const float*)d_in[1];
    const float* fc1b  = (const float*)d_in[2];
    const float* fc2w  = (const float*)d_in[3];
    const float* fc2b  = (const float*)d_in[4];
    const float* fc3w  = (const float*)d_in[5];
    const float* fc3b  = (const float*)d_in[6];
    const float* fc4w  = (const float*)d_in[7];
    const float* fc4b  = (const float*)d_in[8];
    const float* fc5w  = (const float*)d_in[9];
    const float* fc5b  = (const float*)d_in[10];
    const float* lng   = (const float*)d_in[11];
    const float* lnb   = (const float*)d_in[12];
    const float* pcw   = (const float*)d_in[13];
    const float* dww   = (const float*)d_in[14];
    const float* dwb   = (const float*)d_in[15];
    const float* dwbng = (const float*)d_in[16];
    const float* dwbnb = (const float*)d_in[17];
    const float* ddw   = (const float*)d_in[18];
    const float* ddbng = (const float*)d_in[19];
    const float* ddbnb = (const float*)d_in[20];
    const float* sew1  = (const float*)d_in[21];
    const float* seb1  = (const float*)d_in[22];
    const float* sew2  = (const float*)d_in[23];
    const float* seb2  = (const float*)d_in[24];

    float* out  = (float*)d_out;
    float* ws   = (float*)d_ws;
    float* buf0 = ws;                      // xn, later x2
    float* buf1 = ws + (size_t)SZ;         // t1, x_2, d1, y3
    float* buf2 = ws + (size_t)2 * SZ;     // t2, x1, d2
    float* st   = ws + (size_t)3 * SZ;
    float* psumA  = st;          // 2048 (reused for both BN passes)
    float* psqA   = st + 2048;   // 2048
    float* meanc1 = st + 4096;   // 64
    float* rstdc1 = st + 4160;   // 64
    float* meanc2 = st + 4224;   // 64
    float* rstdc2 = st + 4288;   // 64
    float* svec   = st + 4352;   // 2048
    float* evec   = st + 6400;   // 512
    float* pqv    = st + 6912;   // 128

    dim3 blk(256);
    const float* nil = nullptr;

    // xn = transpose(x)
    k_transpose<<<NB * (NHW / 64), blk, 0, stream>>>(x, buf0);
    // P,Q for folded LN
    k_pq<<<1, 64, 0, stream>>>(fc5w, lng, lnb, pqv);
    // t1 = gelu(fc1(roll_h(xn,+1)))
    k_mfc<0, true,  false, false, true, false><<<NPOS / 64, blk, 0, stream>>>(buf0, fc1w, fc1b, nil, nil, nil, nil, nil, buf1);
    // t2 = gelu(fc3(roll_w(xn,-1)))
    k_mfc<2, true,  false, false, true, false><<<NPOS / 64, blk, 0, stream>>>(buf0, fc3w, fc3b, nil, nil, nil, nil, nil, buf2);
    // x_1 = fc2(roll_w(t1,+1)) + xn   (d_out used as scratch, fully rewritten later)
    k_mfc<1, false, true,  false, true, false><<<NPOS / 64, blk, 0, stream>>>(buf1, fc2w, fc2b, buf0, nil, nil, nil, nil, out);
    // x_2 = fc4(roll_h(t2,+1)) + xn
    k_mfc<0, false, true,  false, true, false><<<NPOS / 64, blk, 0, stream>>>(buf2, fc4w, fc4b, buf0, nil, nil, nil, nil, buf1);
    // x1 = LN(concat(x_1,x_2)) @ fc5 + b5 + xn
    k_mln<<<NPOS / 64, blk, 0, stream>>>(out, buf1, fc5w, lng, pqv, fc5b, buf0, buf2);
    // x2 = pc(x1)
    k_mfc<3, false, false, true, false, false><<<NPOS / 64, blk, 0, stream>>>(buf2, pcw, nil, nil, nil, nil, nil, nil, buf0);
    // d1 = dwconv3x3(x2, dil=1) + dw_b   [LDS-tiled, stats fused, no atomics]
    k_dwlds<1, true, false><<<2048, blk, 0, stream>>>(buf0, dww, dwb, nil, nil, nil, nil, buf1, psumA, psqA);
    k_bn_finalize<<<1, 64, 0, stream>>>(psumA, psqA, meanc1, rstdc1);
    // d2 = dwconv3x3(relu(bn1(d1)), dil=2)   [BN+relu at stage time, stats fused]
    k_dwlds<2, false, true><<<2048, blk, 0, stream>>>(buf1, ddw, nil, meanc1, rstdc1, dwbng, dwbnb, buf2, psumA, psqA);
    k_bn_finalize<<<1, 64, 0, stream>>>(psumA, psqA, meanc2, rstdc2);
    // y3 = pc(relu(bn2(d2)))                 [BN+relu fused into load]
    k_mfc<3, false, false, true, false, true><<<NPOS / 64, blk, 0, stream>>>(buf2, pcw, nil, nil, meanc2, rstdc2, ddbng, ddbnb, buf1);
    // SE + final: out = 4*x2*y3*(1+e)
    k_se_reduce<<<NB * NC * 4, blk, 0, stream>>>(buf0, buf1, svec);
    k_se_mlp<<<NB, 64, 0, stream>>>(svec, sew1, seb1, sew2, seb2, evec);
    k_final4<<<SZ / 1024, blk, 0, stream>>>((const float4*)buf0, (const float4*)buf1, evec, (float4*)out);
}

// Round 7
// 152.842 us; speedup vs baseline: 1.8456x; 1.4157x over previous
//
#include <hip/hip_runtime.h>

// Problem constants (fixed by the reference)
constexpr int NB  = 8;
constexpr int NC  = 64;
constexpr int NH  = 128;
constexpr int NW  = 128;
constexpr int NHW = NH * NW;          // 16384
constexpr int CHW = NC * NHW;         // 1048576
constexpr int SZ  = NB * CHW;         // 8388608 elements per tensor
constexpr int NPOS = NB * NHW;        // 131072 spatial positions
constexpr float EPS = 1e-5f;

typedef unsigned short u16;
using bf8   = __attribute__((ext_vector_type(8))) short;   // 8 bf16 = 4 VGPR
using u16x8 = __attribute__((ext_vector_type(8))) u16;
using f32x4 = __attribute__((ext_vector_type(4))) float;

static __device__ inline short f2bf(float f) {
    union { float f; unsigned int u; } v; v.f = f;
    unsigned int r = v.u + 0x7fffu + ((v.u >> 16) & 1u);   // RNE
    return (short)(r >> 16);
}
static __device__ inline float bf2f(u16 u) {
    union { unsigned int i; float f; } v; v.i = ((unsigned int)u) << 16;
    return v.f;
}

// ---------------------------------------------------------------------------
// (B,N,C) fp32 -> (B,C,H,W) bf16 transpose, LDS-tiled
__global__ void k_transpose(const float* __restrict__ x, u16* __restrict__ xn) {
    __shared__ float t[64 * 65];
    int b   = blockIdx.x >> 8;
    int hw0 = (blockIdx.x & 255) << 6;
    int tid = threadIdx.x;
    #pragma unroll
    for (int k = 0; k < 16; ++k) {
        int idx = tid + (k << 8);
        int c = idx & 63, hwl = idx >> 6;
        t[c * 65 + hwl] = x[((size_t)b * NHW + hw0 + hwl) * NC + c];
    }
    __syncthreads();
    #pragma unroll
    for (int k = 0; k < 16; ++k) {
        int idx = tid + (k << 8);
        int hwl = idx & 63, c = idx >> 6;
        xn[(size_t)(b * NC + c) * NHW + hw0 + hwl] = (u16)f2bf(t[c * 65 + hwl]);
    }
}

// ---------------------------------------------------------------------------
// MFMA channel-linear (K=64), bf16 in/out. A = weights (LDS, swizzled),
// B = input (16 positions/wave). Block = 4 waves = 64 pos; grid = NPOS/64.
// MODE 0: rollH (h-c)%H | 1: rollW (w-c)%W | 2: rollW (w+c)%W | 3: no roll
// WTRANS: global weight is [d][c] (pc_w); else [c][d] (fc*)
template<int MODE, bool GELU_OUT, bool WTRANS, bool HASBIAS, bool BNRELU_IN>
__global__ __launch_bounds__(256) void
k_mfc(const u16* __restrict__ in, const float* __restrict__ wgt,
      const float* __restrict__ bias,
      const float* __restrict__ meanc, const float* __restrict__ rstdc,
      const float* __restrict__ bng, const float* __restrict__ bnb,
      u16* __restrict__ out) {
    __shared__ short wt[64 * 64];        // WT[d][c] bf16, swizzled c ^ ((d&7)<<3)
    __shared__ float scl[64], sft[64];
    int tid = threadIdx.x;
    int l = tid & 63, wv = tid >> 6;

    if (!WTRANS) {
        #pragma unroll
        for (int i = 0; i < 8; ++i) {
            int c0 = wv * 2 + i * 8;
            unsigned int pk = (unsigned int)(u16)f2bf(wgt[c0 * 64 + l]) |
                              ((unsigned int)(u16)f2bf(wgt[(c0 + 1) * 64 + l]) << 16);
            *(unsigned int*)&wt[l * 64 + (c0 ^ ((l & 7) << 3))] = pk;
        }
    } else {
        #pragma unroll
        for (int i = 0; i < 16; ++i) {
            int d = wv * 16 + i;
            wt[d * 64 + (l ^ ((d & 7) << 3))] = f2bf(wgt[d * 64 + l]);
        }
    }
    if (BNRELU_IN && tid < 64) {
        float s = rstdc[tid] * bng[tid];
        scl[tid] = s;
        sft[tid] = bnb[tid] - meanc[tid] * s;
    }
    __syncthreads();

    int q = l >> 4, col = l & 15;
    int p  = blockIdx.x * 64 + wv * 16 + col;
    int b  = p >> 14;
    int hw = p & (NHW - 1);
    int h  = hw >> 7, w = hw & 127;
    const u16* inb = in + (size_t)b * CHW;

    f32x4 acc[4];
    #pragma unroll
    for (int dt = 0; dt < 4; ++dt) acc[dt] = (f32x4){0.f, 0.f, 0.f, 0.f};

    #pragma unroll
    for (int ks = 0; ks < 2; ++ks) {
        bf8 bfr;
        #pragma unroll
        for (int j = 0; j < 8; ++j) {
            int c = ks * 32 + q * 8 + j;
            int addr;
            if (MODE == 0)      addr = c * NHW + (((h - c) & 127) << 7) + w;
            else if (MODE == 1) addr = c * NHW + (h << 7) + ((w - c) & 127);
            else if (MODE == 2) addr = c * NHW + (h << 7) + ((w + c) & 127);
            else                addr = c * NHW + hw;
            u16 raw = inb[addr];
            if (BNRELU_IN) {
                float v = fmaxf(bf2f(raw) * scl[c] + sft[c], 0.f);
                bfr[j] = f2bf(v);
            } else {
                bfr[j] = (short)raw;
            }
        }
        #pragma unroll
        for (int dt = 0; dt < 4; ++dt) {
            int d = dt * 16 + col;
            bf8 afr = *(bf8*)&wt[d * 64 + ((ks * 32 + q * 8) ^ ((d & 7) << 3))];
            acc[dt] = __builtin_amdgcn_mfma_f32_16x16x32_bf16(afr, bfr, acc[dt], 0, 0, 0);
        }
    }

    size_t obase = (size_t)b * CHW + hw;
    #pragma unroll
    for (int dt = 0; dt < 4; ++dt) {
        #pragma unroll
        for (int r = 0; r < 4; ++r) {
            int d = dt * 16 + q * 4 + r;
            float val = acc[dt][r];
            if (HASBIAS) val += bias[d];
            if (GELU_OUT) val = 0.5f * val * (1.f + erff(val * 0.70710678118654752f));
            out[obase + (size_t)d * NHW] = (u16)f2bf(val);
        }
    }
}

// ---------------------------------------------------------------------------
// Tiny: P[d] = sum_c g[c]*w5[c][d], Q[d] = sum_c b[c]*w5[c][d]
__global__ void k_pq(const float* __restrict__ w5, const float* __restrict__ lng,
                     const float* __restrict__ lnb, float* __restrict__ PQ) {
    int d = threadIdx.x;   // 64
    float P = 0.f, Q = 0.f;
    for (int c = 0; c < 128; ++c) {
        float wv = w5[c * 64 + d];
        P += lng[c] * wv;
        Q += lnb[c] * wv;
    }
    PQ[d] = P; PQ[64 + d] = Q;
}

// ---------------------------------------------------------------------------
// FUSED fc2 + fc4 + LayerNorm + fc5 (+xn residuals), x_1/x_2 never hit HBM.
// x1out = rstd*(concat(x_1,x_2) @ (g.*W5)) + Q - m*rstd*P + b5 + xn
// where x_1 = fc2(roll_w(t1,+1)) + xn, x_2 = fc4(roll_h(t2,+1)) + xn.
__global__ __launch_bounds__(256) void
k_ffuse(const u16* __restrict__ t1, const u16* __restrict__ t2,
        const u16* __restrict__ xnb,
        const float* __restrict__ fc2w, const float* __restrict__ fc2b,
        const float* __restrict__ fc4w, const float* __restrict__ fc4b,
        const float* __restrict__ w5, const float* __restrict__ lng,
        const float* __restrict__ PQ, const float* __restrict__ b5,
        u16* __restrict__ x1out) {
    __shared__ short wA[64 * 64];    // fc2w [d][c] swz
    __shared__ short wB[64 * 64];    // fc4w [d][c] swz
    __shared__ short wG[64 * 128];   // (g.*w5)[d][c'] swz
    __shared__ short xt[64 * 136];   // per-position concat(x_1,x_2) bf16

    int tid = threadIdx.x;
    int l = tid & 63, wv = tid >> 6;

    #pragma unroll
    for (int i = 0; i < 8; ++i) {
        int c0 = wv * 2 + i * 8;
        unsigned int pa = (unsigned int)(u16)f2bf(fc2w[c0 * 64 + l]) |
                          ((unsigned int)(u16)f2bf(fc2w[(c0 + 1) * 64 + l]) << 16);
        *(unsigned int*)&wA[l * 64 + (c0 ^ ((l & 7) << 3))] = pa;
        unsigned int pb = (unsigned int)(u16)f2bf(fc4w[c0 * 64 + l]) |
                          ((unsigned int)(u16)f2bf(fc4w[(c0 + 1) * 64 + l]) << 16);
        *(unsigned int*)&wB[l * 64 + (c0 ^ ((l & 7) << 3))] = pb;
    }
    #pragma unroll
    for (int i = 0; i < 16; ++i) {
        int c0 = wv * 2 + i * 8;
        unsigned int pk = (unsigned int)(u16)f2bf(lng[c0] * w5[c0 * 64 + l]) |
                          ((unsigned int)(u16)f2bf(lng[c0 + 1] * w5[(c0 + 1) * 64 + l]) << 16);
        *(unsigned int*)&wG[l * 128 + (c0 ^ ((l & 7) << 3))] = pk;
    }
    __syncthreads();

    int q = l >> 4, col = l & 15;
    int p  = blockIdx.x * 64 + wv * 16 + col;
    int b  = p >> 14;
    int hw = p & (NHW - 1);
    int h  = hw >> 7, w = hw & 127;
    size_t base = (size_t)b * CHW;
    int pos = wv * 16 + col;

    // fc2 on roll_w(t1,+1), fc4 on roll_h(t2,+1)
    f32x4 acc1[4], acc2[4];
    #pragma unroll
    for (int dt = 0; dt < 4; ++dt) {
        acc1[dt] = (f32x4){0.f, 0.f, 0.f, 0.f};
        acc2[dt] = (f32x4){0.f, 0.f, 0.f, 0.f};
    }
    #pragma unroll
    for (int ks = 0; ks < 2; ++ks) {
        bf8 f1, f2;
        #pragma unroll
        for (int j = 0; j < 8; ++j) {
            int c = ks * 32 + q * 8 + j;
            f1[j] = (short)t1[base + c * NHW + (h << 7) + ((w - c) & 127)];
            f2[j] = (short)t2[base + c * NHW + (((h - c) & 127) << 7) + w];
        }
        #pragma unroll
        for (int dt = 0; dt < 4; ++dt) {
            int d = dt * 16 + col;
            int wo = (ks * 32 + q * 8) ^ ((d & 7) << 3);
            acc1[dt] = __builtin_amdgcn_mfma_f32_16x16x32_bf16(*(bf8*)&wA[d * 64 + wo], f1, acc1[dt], 0, 0, 0);
            acc2[dt] = __builtin_amdgcn_mfma_f32_16x16x32_bf16(*(bf8*)&wB[d * 64 + wo], f2, acc2[dt], 0, 0, 0);
        }
    }

    // xn residuals for this lane's 16 (d, pos) outputs
    float xr[16];
    #pragma unroll
    for (int dt = 0; dt < 4; ++dt)
        #pragma unroll
        for (int r = 0; r < 4; ++r)
            xr[dt * 4 + r] = bf2f(xnb[base + (size_t)(dt * 16 + q * 4 + r) * NHW + hw]);

    // x_1/x_2 values, LN partial stats, write to xt (bf16)
    float s = 0.f, sq = 0.f;
    #pragma unroll
    for (int dt = 0; dt < 4; ++dt) {
        float v1[4], v2[4];
        #pragma unroll
        for (int r = 0; r < 4; ++r) {
            int d = dt * 16 + q * 4 + r;
            v1[r] = acc1[dt][r] + fc2b[d] + xr[dt * 4 + r];
            v2[r] = acc2[dt][r] + fc4b[d] + xr[dt * 4 + r];
            s += v1[r] + v2[r];
            sq += v1[r] * v1[r] + v2[r] * v2[r];
        }
        unsigned int pk0 = (unsigned int)(u16)f2bf(v1[0]) | ((unsigned int)(u16)f2bf(v1[1]) << 16);
        unsigned int pk1 = (unsigned int)(u16)f2bf(v1[2]) | ((unsigned int)(u16)f2bf(v1[3]) << 16);
        *(uint2*)&xt[pos * 136 + dt * 16 + q * 4] = make_uint2(pk0, pk1);
        unsigned int pk2 = (unsigned int)(u16)f2bf(v2[0]) | ((unsigned int)(u16)f2bf(v2[1]) << 16);
        unsigned int pk3 = (unsigned int)(u16)f2bf(v2[2]) | ((unsigned int)(u16)f2bf(v2[3]) << 16);
        *(uint2*)&xt[pos * 136 + 64 + dt * 16 + q * 4] = make_uint2(pk2, pk3);
    }
    s  += __shfl_xor(s, 16);  s += __shfl_xor(s, 32);
    sq += __shfl_xor(sq, 16); sq += __shfl_xor(sq, 32);
    float m    = s * (1.f / 128.f);
    float var  = sq * (1.f / 128.f) - m * m;
    float rstd = rsqrtf(var + EPS);
    float mr   = m * rstd;
    __syncthreads();

    // fc5 (K=128) from LDS
    f32x4 acc[4];
    #pragma unroll
    for (int dt = 0; dt < 4; ++dt) acc[dt] = (f32x4){0.f, 0.f, 0.f, 0.f};
    #pragma unroll
    for (int ks = 0; ks < 4; ++ks) {
        bf8 bfr = *(bf8*)&xt[pos * 136 + ks * 32 + q * 8];
        #pragma unroll
        for (int dt = 0; dt < 4; ++dt) {
            int d = dt * 16 + col;
            bf8 afr = *(bf8*)&wG[d * 128 + ((ks * 32 + q * 8) ^ ((d & 7) << 3))];
            acc[dt] = __builtin_amdgcn_mfma_f32_16x16x32_bf16(afr, bfr, acc[dt], 0, 0, 0);
        }
    }

    size_t obase = base + hw;
    #pragma unroll
    for (int dt = 0; dt < 4; ++dt) {
        #pragma unroll
        for (int r = 0; r < 4; ++r) {
            int d = dt * 16 + q * 4 + r;
            float val = rstd * acc[dt][r] + PQ[64 + d] - mr * PQ[d] + b5[d] + xr[dt * 4 + r];
            x1out[obase + (size_t)d * NHW] = (u16)f2bf(val);
        }
    }
}

// ---------------------------------------------------------------------------
// Depthwise 3x3 conv, LDS-tiled, bf16 in/out. Block = 32 rows of one plane.
// Stats (fp32, pre-rounding) -> per-block partials (no atomics).
template<int DIL, bool HASBIAS, bool BNIN>
__global__ __launch_bounds__(256) void
k_dwlds(const u16* __restrict__ in, const float* __restrict__ wgt,
        const float* __restrict__ bias,
        const float* __restrict__ meanc, const float* __restrict__ rstdc,
        const float* __restrict__ bng, const float* __restrict__ bnb,
        u16* __restrict__ out, float* __restrict__ psum, float* __restrict__ psq) {
    constexpr int STR = 136;                  // 4 pad | 128 | 4 pad
    __shared__ float tile[36 * STR];
    __shared__ float ss[256], sq[256];

    int blk = ((blockIdx.x & 7) << 8) | (blockIdx.x >> 3);  // XCD chunk swizzle
    int q   = blk & 3;
    int bc  = blk >> 2;
    int c   = bc & 63;
    int r0  = q * 32;
    int tid = threadIdx.x;
    const u16* ip = in + (size_t)bc * NHW;

    float scale = 0.f, shift = 0.f;
    if (BNIN) { scale = rstdc[c] * bng[c]; shift = bnb[c] - meanc[c] * scale; }

    // stage rows r0-2 .. r0+33 (8 bf16 units), BN+relu at stage time
    #pragma unroll 1
    for (int idx = tid; idx < 36 * 16; idx += 256) {
        int lr = idx >> 4, u = idx & 15;
        int gr = r0 - 2 + lr;
        float v[8] = {0.f, 0.f, 0.f, 0.f, 0.f, 0.f, 0.f, 0.f};
        if (gr >= 0 && gr < NH) {
            u16x8 raw = *(const u16x8*)(ip + gr * NW + u * 8);
            #pragma unroll
            for (int j = 0; j < 8; ++j) {
                float f = bf2f(raw[j]);
                if (BNIN) f = fmaxf(f * scale + shift, 0.f);
                v[j] = f;
            }
        }
        *(float4*)&tile[lr * STR + 4 + u * 8]     = make_float4(v[0], v[1], v[2], v[3]);
        *(float4*)&tile[lr * STR + 4 + u * 8 + 4] = make_float4(v[4], v[5], v[6], v[7]);
        if (u == 0)  *(float4*)&tile[lr * STR]       = make_float4(0.f, 0.f, 0.f, 0.f);
        if (u == 15) *(float4*)&tile[lr * STR + 132] = make_float4(0.f, 0.f, 0.f, 0.f);
    }
    __syncthreads();

    float wc[9];
    #pragma unroll
    for (int k = 0; k < 9; ++k) wc[k] = wgt[c * 9 + k];

    int row  = tid >> 3;
    int col0 = (tid & 7) * 16;
    float o[16];
    float bb = HASBIAS ? bias[c] : 0.f;
    #pragma unroll
    for (int j = 0; j < 16; ++j) o[j] = bb;

    #pragma unroll
    for (int i = 0; i < 3; ++i) {
        const float* rp = &tile[(row + 2 + (i - 1) * DIL) * STR + 4 + col0];
        float4 A  = *(const float4*)(rp - 4);
        float4 B0 = *(const float4*)(rp);
        float4 B1 = *(const float4*)(rp + 4);
        float4 B2 = *(const float4*)(rp + 8);
        float4 B3 = *(const float4*)(rp + 12);
        float4 Cc = *(const float4*)(rp + 16);
        float ww[24] = {A.x,A.y,A.z,A.w, B0.x,B0.y,B0.z,B0.w, B1.x,B1.y,B1.z,B1.w,
                        B2.x,B2.y,B2.z,B2.w, B3.x,B3.y,B3.z,B3.w, Cc.x,Cc.y,Cc.z,Cc.w};
        float w0 = wc[3 * i], w1 = wc[3 * i + 1], w2 = wc[3 * i + 2];
        #pragma unroll
        for (int j = 0; j < 16; ++j)
            o[j] += w0 * ww[4 + j - DIL] + w1 * ww[4 + j] + w2 * ww[4 + j + DIL];
    }

    u16* op = out + (size_t)bc * NHW + (r0 + row) * NW + col0;
    u16x8 o1, o2;
    #pragma unroll
    for (int j = 0; j < 8; ++j) { o1[j] = (u16)f2bf(o[j]); o2[j] = (u16)f2bf(o[8 + j]); }
    *(u16x8*)(op)     = o1;
    *(u16x8*)(op + 8) = o2;

    float s = 0.f, qq = 0.f;
    #pragma unroll
    for (int j = 0; j < 16; ++j) { s += o[j]; qq += o[j] * o[j]; }
    ss[tid] = s; sq[tid] = qq; __syncthreads();
    for (int off = 128; off > 0; off >>= 1) {
        if (tid < off) { ss[tid] += ss[tid + off]; sq[tid] += sq[tid + off]; }
        __syncthreads();
    }
    if (tid == 0) { psum[blk] = ss[0]; psq[blk] = sq[0]; }
}

__global__ void k_bn_finalize(const float* __restrict__ psum, const float* __restrict__ psq,
                              float* __restrict__ meanc, float* __restrict__ rstdc) {
    int c = threadIdx.x;  // 64 threads
    float s = 0.f, qv = 0.f;
    for (int b = 0; b < NB; ++b)
        #pragma unroll
        for (int j = 0; j < 4; ++j) {
            int idx = ((b * 64 + c) << 2) + j;
            s += psum[idx]; qv += psq[idx];
        }
    const float inv = 1.f / (float)(NB * NHW);
    float m = s * inv;
    float v = qv * inv - m * m;
    meanc[c] = m;
    rstdc[c] = rsqrtf(v + EPS);
}

// ---------------------------------------------------------------------------
// SE partial: s4[bc*4+q] = sum_{quarter} x2*y3 ; grid = 2048, bf16 inputs
__global__ void k_se_reduce(const u16* __restrict__ x2, const u16* __restrict__ y3,
                            float* __restrict__ s4) {
    __shared__ float ss[256];
    int q   = blockIdx.x & 3;
    int bc  = blockIdx.x >> 2;
    int tid = threadIdx.x;
    const u16* a  = x2 + (size_t)bc * NHW + q * (NHW / 4);
    const u16* b_ = y3 + (size_t)bc * NHW + q * (NHW / 4);
    float acc = 0.f;
    #pragma unroll
    for (int i = 0; i < 2; ++i) {
        u16x8 av = *(const u16x8*)(a + (tid + i * 256) * 8);
        u16x8 bv = *(const u16x8*)(b_ + (tid + i * 256) * 8);
        #pragma unroll
        for (int j = 0; j < 8; ++j) acc += bf2f(av[j]) * bf2f(bv[j]);
    }
    ss[tid] = acc; __syncthreads();
    for (int o = 128; o > 0; o >>= 1) {
        if (tid < o) ss[tid] += ss[tid + o];
        __syncthreads();
    }
    if (tid == 0) s4[blockIdx.x] = ss[0];
}

// e[b,c] = sigmoid(W2 @ relu(W1 @ s + b1) + b2) ; one block (64 threads) per b
__global__ void k_se_mlp(const float* __restrict__ s4, const float* __restrict__ w1,
                         const float* __restrict__ b1, const float* __restrict__ w2,
                         const float* __restrict__ b2, float* __restrict__ e) {
    __shared__ float sh[64], e1[8];
    int b = blockIdx.x, tid = threadIdx.x;
    float sv = 0.f;
    #pragma unroll
    for (int j = 0; j < 4; ++j) sv += s4[(b * 64 + tid) * 4 + j];
    sh[tid] = sv * (4.f / (float)NHW);
    __syncthreads();
    if (tid < 8) {
        float a = b1[tid];
        for (int c = 0; c < 64; ++c) a += sh[c] * w1[tid * 64 + c];
        e1[tid] = a > 0.f ? a : 0.f;
    }
    __syncthreads();
    float a = b2[tid];
    #pragma unroll
    for (int j = 0; j < 8; ++j) a += e1[j] * w2[tid * 8 + j];
    e[b * 64 + tid] = 1.f / (1.f + expf(-a));
}

// out = 4*x2*y3*(1+e), bf16 in -> fp32 out, 8 elems/thread
__global__ void k_final8(const u16* __restrict__ x2, const u16* __restrict__ y3,
                         const float* __restrict__ e, float* __restrict__ out) {
    int t  = blockIdx.x * 256 + threadIdx.x;   // over SZ/8
    int bc = t >> 11;
    float f = 4.f * (1.f + e[bc]);
    u16x8 av = *(const u16x8*)(x2 + (size_t)t * 8);
    u16x8 bv = *(const u16x8*)(y3 + (size_t)t * 8);
    float4 o0, o1;
    o0.x = f * bf2f(av[0]) * bf2f(bv[0]); o0.y = f * bf2f(av[1]) * bf2f(bv[1]);
    o0.z = f * bf2f(av[2]) * bf2f(bv[2]); o0.w = f * bf2f(av[3]) * bf2f(bv[3]);
    o1.x = f * bf2f(av[4]) * bf2f(bv[4]); o1.y = f * bf2f(av[5]) * bf2f(bv[5]);
    o1.z = f * bf2f(av[6]) * bf2f(bv[6]); o1.w = f * bf2f(av[7]) * bf2f(bv[7]);
    *(float4*)(out + (size_t)t * 8)     = o0;
    *(float4*)(out + (size_t)t * 8 + 4) = o1;
}

// ---------------------------------------------------------------------------
extern "C" void kernel_launch(void* const* d_in, const int* in_sizes, int n_in,
                              void* d_out, int out_size, void* d_ws, size_t ws_size,
                              hipStream_t stream) {
    const float* x     = (const float*)d_in[0];
    const float* fc1w  = (const float*)d_in[1];
    const float* fc1b  = (const float*)d_in[2];
    const float* fc2w  = (const float*)d_in[3];
    const float* fc2b  = (const float*)d_in[4];
    const float* fc3w  = (const float*)d_in[5];
    const float* fc3b  = (const float*)d_in[6];
    const float* fc4w  = (const float*)d_in[7];
    const float* fc4b  = (const float*)d_in[8];
    const float* fc5w  = (const float*)d_in[9];
    const float* fc5b  = (const float*)d_in[10];
    const float* lng   = (const float*)d_in[11];
    const float* lnb   = (const float*)d_in[12];
    const float* pcw   = (const float*)d_in[13];
    const float* dww   = (const float*)d_in[14];
    const float* dwb   = (const float*)d_in[15];
    const float* dwbng = (const float*)d_in[16];
    const float* dwbnb = (const float*)d_in[17];
    const float* ddw   = (const float*)d_in[18];
    const float* ddbng = (const float*)d_in[19];
    const float* ddbnb = (const float*)d_in[20];
    const float* sew1  = (const float*)d_in[21];
    const float* seb1  = (const float*)d_in[22];
    const float* sew2  = (const float*)d_in[23];
    const float* seb2  = (const float*)d_in[24];

    float* out = (float*)d_out;
    u16* wsu = (u16*)d_ws;
    u16* bufA = wsu;                     // xn -> x2
    u16* bufB = wsu + (size_t)SZ;        // t1 -> d1
    u16* bufC = wsu + (size_t)2 * SZ;    // t2 -> d2
    u16* bufD = wsu + (size_t)3 * SZ;    // x1 -> y3
    float* st = (float*)(wsu + (size_t)4 * SZ);
    float* psumA  = st;          // 2048
    float* psqA   = st + 2048;   // 2048
    float* meanc1 = st + 4096;   // 64
    float* rstdc1 = st + 4160;   // 64
    float* meanc2 = st + 4224;   // 64
    float* rstdc2 = st + 4288;   // 64
    float* svec   = st + 4352;   // 2048
    float* evec   = st + 6400;   // 512
    float* pqv    = st + 6912;   // 128

    dim3 blk(256);
    const float* nil = nullptr;

    // xn = transpose(x) -> bf16
    k_transpose<<<NB * (NHW / 64), blk, 0, stream>>>(x, bufA);
    // P,Q for folded LN
    k_pq<<<1, 64, 0, stream>>>(fc5w, lng, lnb, pqv);
    // t1 = gelu(fc1(roll_h(xn,+1)))
    k_mfc<0, true,  false, true, false><<<NPOS / 64, blk, 0, stream>>>(bufA, fc1w, fc1b, nil, nil, nil, nil, bufB);
    // t2 = gelu(fc3(roll_w(xn,-1)))
    k_mfc<2, true,  false, true, false><<<NPOS / 64, blk, 0, stream>>>(bufA, fc3w, fc3b, nil, nil, nil, nil, bufC);
    // x1 = fused fc2+fc4+LN+fc5 (+xn residuals)
    k_ffuse<<<NPOS / 64, blk, 0, stream>>>(bufB, bufC, bufA, fc2w, fc2b, fc4w, fc4b,
                                           fc5w, lng, pqv, fc5b, bufD);
    // x2 = pc(x1)
    k_mfc<3, false, true, false, false><<<NPOS / 64, blk, 0, stream>>>(bufD, pcw, nil, nil, nil, nil, nil, bufA);
    // d1 = dwconv3x3(x2, dil=1) + dw_b   [stats fused]
    k_dwlds<1, true, false><<<2048, blk, 0, stream>>>(bufA, dww, dwb, nil, nil, nil, nil, bufB, psumA, psqA);
    k_bn_finalize<<<1, 64, 0, stream>>>(psumA, psqA, meanc1, rstdc1);
    // d2 = dwconv3x3(relu(bn1(d1)), dil=2)   [BN+relu at stage time, stats fused]
    k_dwlds<2, false, true><<<2048, blk, 0, stream>>>(bufB, ddw, nil, meanc1, rstdc1, dwbng, dwbnb, bufC, psumA, psqA);
    k_bn_finalize<<<1, 64, 0, stream>>>(psumA, psqA, meanc2, rstdc2);
    // y3 = pc(relu(bn2(d2)))
    k_mfc<3, false, true, false, true><<<NPOS / 64, blk, 0, stream>>>(bufC, pcw, nil, meanc2, rstdc2, ddbng, ddbnb, bufD);
    // SE + final: out = 4*x2*y3*(1+e)
    k_se_reduce<<<NB * NC * 4, blk, 0, stream>>>(bufA, bufD, svec);
    k_se_mlp<<<NB, 64, 0, stream>>>(svec, sew1, seb1, sew2, seb2, evec);
    k_final8<<<SZ / 2048, blk, 0, stream>>>(bufA, bufD, evec, out);
}